// Round 15
// baseline (79.364 us; speedup 1.0000x reference)
//
#include <hip/hip_runtime.h>

#define DEV __device__ __forceinline__

typedef __attribute__((ext_vector_type(8)))  short bf16x8;
typedef __attribute__((ext_vector_type(4)))  short s16x4;
typedef __attribute__((ext_vector_type(16))) float f32x16;

constexpr int SB = 2;            // batch
constexpr int SS = 4096;         // seq len
constexpr int SH = 256;          // hidden
constexpr int NHEAD = 8, HD = 32;
constexpr int M_TOK = SB * SS;   // 8192 token rows
constexpr int NQKV = 3 * SH;     // 768

// ---- workspace layout (bytes) ----
constexpr size_t OFF_CNT  = 0;                                 // int[4]: pad cnt, real cnt
constexpr size_t OFF_BIAS = 256;                               // spare
constexpr size_t OFF_XB   = OFF_BIAS + 32768;                  // bf16[8192*256]; later Kc
constexpr size_t OFF_WQKV = OFF_XB + (size_t)M_TOK * SH * 2;   // bf16[768*256]
constexpr size_t OFF_BQKV = OFF_WQKV + (size_t)NQKV * SH * 2;  // f32[768] (pad 4096)
constexpr size_t OFF_WOB  = OFF_BQKV + 4096;                   // bf16[256*256]
constexpr size_t OFF_BO   = OFF_WOB + (size_t)SH * SH * 2;     // f32[256] (pad 1024)
constexpr size_t OFF_Q    = OFF_BO + 1024;                     // bf16 [16][4096][32]
constexpr size_t OFF_K    = OFF_Q + (size_t)M_TOK * SH * 2;    // K; later OP0
constexpr size_t OFF_V    = OFF_K + (size_t)M_TOK * SH * 2;    // V row-major; later OP1
constexpr size_t OFF_VT   = OFF_V + (size_t)M_TOK * SH * 2;    // bf16 [16][32][4096] (compacted)
constexpr size_t OFF_O    = OFF_VT + (size_t)M_TOK * SH * 2;   // idxC (32KB) then f32 Lp[2][16][4096]
constexpr size_t WS_NEED  = OFF_O + (size_t)M_TOK * SH * 2;

// ---- helpers ----
DEV short f2bf(float f) {                      // RNE f32 -> bf16 bits
  unsigned u = __builtin_bit_cast(unsigned, f);
  u = (u + 0x7FFFu + ((u >> 16) & 1u)) >> 16;
  return (short)u;
}

DEV float bf2f(short s) {
  return __builtin_bit_cast(float, ((unsigned)(unsigned short)s) << 16);
}

DEV float exp2_(float x) {                     // trans-pipe exp2
#if __has_builtin(__builtin_amdgcn_exp2f)
  return __builtin_amdgcn_exp2f(x);
#else
  float r;
  asm("v_exp_f32 %0, %1\n\ts_nop 0" : "=v"(r) : "v"(x));
  return r;
#endif
}

DEV float rcp_(float x) {                      // approx 1/x (rel err ~1e-7)
#if __has_builtin(__builtin_amdgcn_rcpf)
  return __builtin_amdgcn_rcpf(x);
#else
  float r;
  asm("v_rcp_f32 %0, %1\n\ts_nop 0" : "=v"(r) : "v"(x));
  return r;
#endif
}

DEV unsigned cvtpk(float lo, float hi) {       // {bf16(lo), bf16(hi)} packed
  unsigned r;
  asm("v_cvt_pk_bf16_f32 %0, %1, %2" : "=v"(r) : "v"(lo), "v"(hi));
  return r;
}

DEV void plswap(unsigned& a, unsigned& b) {    // v_permlane32_swap_b32 a, b
  asm("v_permlane32_swap_b32 %0, %1" : "+v"(a), "+v"(b));
}

DEV float bperm_f(int srclane, float v) {
  int r = __builtin_amdgcn_ds_bpermute(srclane * 4, __builtin_bit_cast(int, v));
  return __builtin_bit_cast(float, r);
}

// ---- 1. fused prep + mask-scan (verified round 12) ----
__global__ void prep_scan_kernel(const float* __restrict__ x,
    const float* __restrict__ wq, const float* __restrict__ bq,
    const float* __restrict__ wk, const float* __restrict__ bk,
    const float* __restrict__ wv, const float* __restrict__ bv,
    const float* __restrict__ wo, const float* __restrict__ bo,
    short* __restrict__ xb, short* __restrict__ Wqkv, float* __restrict__ bqkv,
    short* __restrict__ wob, float* __restrict__ bof,
    const unsigned char* __restrict__ m, int* __restrict__ idxC,
    int* __restrict__ cnts) {
  const int tid = threadIdx.x;
  if (blockIdx.x < 2) {
    __shared__ int f_mis, f_off4, f_3f;
    __shared__ int ts[256];
    const int b = blockIdx.x;
    if (tid == 0) { f_mis = 0; f_off4 = 0; f_3f = 0; }
    __syncthreads();
    int lm = 0, lo4 = 0, l3f = 0;
    for (int i = tid; i < 8192; i += 256) {
      unsigned char c = m[i];
      if (c) {
        if (i & 3) lm = 1;
        if ((i & 7) == 4) lo4 = 1;
        if ((i & 3) == 3 && c == 0x3F) l3f = 1;
      }
    }
    if (lm)  atomicOr(&f_mis, 1);
    if (lo4) atomicOr(&f_off4, 1);
    if (l3f) atomicOr(&f_3f, 1);
    __syncthreads();
    const int f = !f_mis ? (f_off4 ? 1 : 3) : (f_3f ? 2 : 0);  // 0=u8 1=i32 2=f32 3=i64
    int bits = 0;
    const int rbase = b * 4096 + tid * 16;
#pragma unroll
    for (int j = 0; j < 16; ++j) {
      int r = rbase + j;
      bool on;
      if (f == 0)      on = m[r] != 0;
      else if (f == 1) on = m[(size_t)r * 4] != 0;
      else if (f == 2) on = m[(size_t)r * 4 + 3] != 0;
      else             on = m[(size_t)r * 8] != 0;
      bits |= (int)on << j;
    }
    const int cnt = __popc(bits);
    ts[tid] = cnt;
    __syncthreads();
    for (int off = 1; off < 256; off <<= 1) {
      int u = (tid >= off) ? ts[tid - off] : 0;
      __syncthreads();
      ts[tid] += u;
      __syncthreads();
    }
    const int total = ts[255];
    int pos = ts[tid] - cnt;   // exclusive
    int* idxB = idxC + b * 4096;
    if (total == 0) {
      for (int j = tid; j < 4096; j += 256) idxB[j] = j;
      if (tid == 0) { cnts[b] = 4096; cnts[2 + b] = 4096; }
      return;
    }
#pragma unroll
    for (int j = 0; j < 16; ++j)
      if ((bits >> j) & 1) { idxB[pos] = tid * 16 + j; ++pos; }
    int cntpad = (total + 255) & ~255;
    if (cntpad < 256) cntpad = 256;
    for (int j = total + tid; j < cntpad; j += 256) idxB[j] = -1;
    if (tid == 0) { cnts[b] = cntpad; cnts[2 + b] = total; }
    return;
  }
  const float QS = (float)(1.4426950408889634 / 5.656854249492381);  // log2(e)/sqrt(32)
  long i = ((long)(blockIdx.x - 2) * 256 + tid) * 8;
  const long NX = (long)M_TOK * SH;
  const long NW = (long)NQKV * SH;
  if (i < NX) {
    const float4* s = (const float4*)(x + i);
    float4 f0 = s[0], f1 = s[1];
    bf16x8 o;
    o[0]=f2bf(f0.x); o[1]=f2bf(f0.y); o[2]=f2bf(f0.z); o[3]=f2bf(f0.w);
    o[4]=f2bf(f1.x); o[5]=f2bf(f1.y); o[6]=f2bf(f1.z); o[7]=f2bf(f1.w);
    *(bf16x8*)(xb + i) = o;
    return;
  }
  i -= NX;
  if (i < NW) {
    int n = (int)(i >> 8), kk = (int)(i & 255);
    int tn = n >> 8, rr = n & 255;
    const float* src = (tn == 0 ? wq : (tn == 1 ? wk : wv)) + rr * 256 + kk;
    float sc = tn == 0 ? QS : 1.f;
    float4 f0 = *(const float4*)src, f1 = *(const float4*)(src + 4);
    bf16x8 o;
    o[0]=f2bf(f0.x*sc); o[1]=f2bf(f0.y*sc); o[2]=f2bf(f0.z*sc); o[3]=f2bf(f0.w*sc);
    o[4]=f2bf(f1.x*sc); o[5]=f2bf(f1.y*sc); o[6]=f2bf(f1.z*sc); o[7]=f2bf(f1.w*sc);
    *(bf16x8*)(Wqkv + i) = o;
    return;
  }
  i -= NW;
  if (i < NQKV) {
    int n = (int)i;
#pragma unroll
    for (int j = 0; j < 8; ++j) {
      int nn = n + j, tn = nn >> 8, rr = nn & 255;
      const float* src = tn == 0 ? bq : (tn == 1 ? bk : bv);
      bqkv[nn] = src[rr] * (tn == 0 ? QS : 1.f);
    }
    return;
  }
  i -= NQKV;
  if (i < (long)SH * SH) {
    const float4* s = (const float4*)(wo + i);
    float4 f0 = s[0], f1 = s[1];
    bf16x8 o;
    o[0]=f2bf(f0.x); o[1]=f2bf(f0.y); o[2]=f2bf(f0.z); o[3]=f2bf(f0.w);
    o[4]=f2bf(f1.x); o[5]=f2bf(f1.y); o[6]=f2bf(f1.z); o[7]=f2bf(f1.w);
    *(bf16x8*)(wob + i) = o;
    return;
  }
  i -= (long)SH * SH;
  if (i < SH) {
#pragma unroll
    for (int j = 0; j < 8; ++j) bof[i + j] = bo[i + j];
  }
}

// ---- 2/5. GEMM 64x64 tile, BK=64, 4 waves (2x2), 1 acc/wave ----
// Same verified 2-barrier skeleton + register staging; tile shrunk so the
// grid gives 6 blocks/CU (gemm<0>) / 2 blocks/CU (gemm<1>) for cross-block
// latency hiding (K=256 -> only 4 K-steps, pipeline never warms in-block).
// MODE 1 fuses split-combine into A staging.
template <int MODE>
__global__ __launch_bounds__(256) void gemm_kernel(
    const short* __restrict__ Ag, const short* __restrict__ Bg,
    const float* __restrict__ bias,
    short* __restrict__ q, short* __restrict__ k, short* __restrict__ v,
    float* __restrict__ outf,
    const short* __restrict__ P1, const float* __restrict__ Lp,
    const int* __restrict__ cnts) {
  __shared__ __align__(16) short lA[4096];   // [kg 0..7][m 0..63] x8  (8KB)
  __shared__ __align__(16) short lB[4096];   // [kg 0..7][n 0..63] x8  (8KB)
  const int tid = threadIdx.x;
  const int lane = tid & 63, w = tid >> 6;
  const int wm = w >> 1, wn = w & 1;
  const int hi = lane >> 5, l31 = lane & 31;
  const int mb = blockIdx.x, nb = blockIdx.y;
  f32x16 acc;
#pragma unroll
  for (int i = 0; i < 16; ++i) acc[i] = 0.f;
  float npadv[2] = {0.f, 0.f};
  if constexpr (MODE == 1) {
    npadv[0] = (float)(cnts[0] - cnts[2]);
    npadv[1] = (float)(cnts[1] - cnts[3]);
  }
  bf16x8 ra[2], rb[2];
  const int am = tid >> 3, ak = tid & 7;   // am 0..31, ak 0..7
  auto gload = [&](int kb) {
#pragma unroll
    for (int p = 0; p < 2; ++p) {
      if constexpr (MODE == 0) {
        ra[p] = *(const bf16x8*)(Ag + (size_t)(mb * 64 + p * 32 + am) * 256 + kb * 64 + ak * 8);
      } else {
        const int row = mb * 64 + p * 32 + am;
        const int bb = row >> 12, ss = row & 4095;
        const int colb = kb * 64 + ak * 8;
        const int bhh = bb * 8 + (colb >> 5);
        float l = Lp[(size_t)bhh * SS + ss] + Lp[(size_t)(16 + bhh) * SS + ss] - npadv[bb];
        float rc = rcp_(l);
        bf16x8 o0 = *(const bf16x8*)(Ag + (size_t)row * 256 + colb);
        bf16x8 o1 = *(const bf16x8*)(P1 + (size_t)row * 256 + colb);
        bf16x8 o;
#pragma unroll
        for (int j = 0; j < 8; ++j) o[j] = f2bf((bf2f(o0[j]) + bf2f(o1[j])) * rc);
        ra[p] = o;
      }
    }
#pragma unroll
    for (int p = 0; p < 2; ++p)
      rb[p] = *(const bf16x8*)(Bg + (size_t)(nb * 64 + p * 32 + am) * 256 + kb * 64 + ak * 8);
  };
  gload(0);
  for (int kb = 0; kb < 4; ++kb) {
    __syncthreads();
#pragma unroll
    for (int p = 0; p < 2; ++p)
      *(bf16x8*)(lA + (ak * 64 + p * 32 + am) * 8) = ra[p];
#pragma unroll
    for (int p = 0; p < 2; ++p)
      *(bf16x8*)(lB + (ak * 64 + p * 32 + am) * 8) = rb[p];
    __syncthreads();
    if (kb < 3) gload(kb + 1);
#pragma unroll
    for (int ks = 0; ks < 4; ++ks) {
      const int kg = 2 * ks + hi;
      bf16x8 af = *(const bf16x8*)(lA + (kg * 64 + wm * 32 + l31) * 8);
      bf16x8 bf = *(const bf16x8*)(lB + (kg * 64 + wn * 32 + l31) * 8);
      acc = __builtin_amdgcn_mfma_f32_32x32x16_bf16(af, bf, acc, 0, 0, 0);
    }
  }
  const int ncol = nb * 64 + wn * 32 + l31;
  const float bval = bias[ncol];
  if (MODE == 0) {
    const int tensor = nb >> 2;                       // 0=Q 1=K 2=V
    short* dst = tensor == 0 ? q : (tensor == 1 ? k : v);
    const int a = (nb & 3) * 64 + wn * 32 + l31;      // feature within 256
    const int hh = a >> 5, d = a & 31;
#pragma unroll
    for (int r = 0; r < 16; ++r) {
      int gm = mb * 64 + wm * 32 + (r & 3) + 8 * (r >> 2) + 4 * hi;
      int bb = gm >> 12, ss = gm & 4095;
      dst[(((size_t)bb * NHEAD + hh) * SS + ss) * HD + d] = f2bf(acc[r] + bval);
    }
  } else {
#pragma unroll
    for (int r = 0; r < 16; ++r) {
      int gm = mb * 64 + wm * 32 + (r & 3) + 8 * (r >> 2) + 4 * hi;
      outf[(size_t)gm * SH + ncol] = acc[r] + bval;
    }
  }
}

// ---- 3. fused gather-K + gather-transpose-V (pad rows = 0) ----
__global__ __launch_bounds__(256) void gather_kv_kernel(const short* __restrict__ K,
    const short* __restrict__ V, const int* __restrict__ idxC, const int* __restrict__ cnts,
    short* __restrict__ Kc, short* __restrict__ Vt) {
  const int bh = blockIdx.y, b = bh >> 3;
  const int jb = blockIdx.x * 64;
  if (jb >= cnts[b]) return;
  __shared__ short t[64][33];
  const int tid = threadIdx.x;
  const int s = tid >> 2, g = tid & 3;
  const int ix = idxC[b * 4096 + jb + s];
  bf16x8 kvv{}, vvv{};
  if (ix >= 0) {
    kvv = *(const bf16x8*)(K + ((size_t)bh * SS + ix) * HD + g * 8);
    vvv = *(const bf16x8*)(V + ((size_t)bh * SS + ix) * HD + g * 8);
  }
  *(bf16x8*)(Kc + ((size_t)bh * SS + jb + s) * HD + g * 8) = kvv;
#pragma unroll
  for (int j = 0; j < 8; ++j) t[s][g * 8 + j] = vvv[j];
  __syncthreads();
  const int d = tid >> 3, gs = tid & 7;
  bf16x8 out;
#pragma unroll
  for (int j = 0; j < 8; ++j) out[j] = t[gs * 8 + j][d];
  *(bf16x8*)(Vt + ((size_t)bh * HD + d) * SS + jb + gs * 8) = out;
}

// ---- 4. flash attention, split x2, KVBLK=128, dual q-stream, scalar lsum,
//         s_setprio around MFMA clusters (round-14 verified) ----
__global__ __launch_bounds__(256, 2) void attn_kernel(const short* __restrict__ Q,
    const short* __restrict__ Kc, const short* __restrict__ Vt,
    const int* __restrict__ cnts,
    short* __restrict__ OP0, short* __restrict__ OP1, float* __restrict__ Lp) {
  __shared__ __align__(16) short sK[4096];   // [gd 0..3][kv 0..127] x8
  __shared__ __align__(16) short sV[4096];   // [gkv 0..15][d 0..31] x8
  const int tid = threadIdx.x;
  const int lane = tid & 63, wave = tid >> 6;
  const int hi = lane >> 5, l31 = lane & 31;
  const int qblk = blockIdx.x, bh = blockIdx.y, half = blockIdx.z;
  const int b = bh >> 3, h = bh & 7;
  const int Lh = cnts[b] >> 1;          // multiple of 128
  const int NIT = Lh >> 7;
  const int kv0 = half * Lh;
  const short* Kb = Kc + ((size_t)bh * SS + kv0) * HD;
  const short* Vb = Vt + (size_t)bh * HD * SS + kv0;
  const int qbase = qblk * 256 + wave * 64;     // this wave: q rows [qbase, qbase+64)
  const short* QrowA = Q + ((size_t)bh * SS + qbase + l31) * HD;
  const short* QrowB = QrowA + 32 * HD;
  const bf16x8 qa0 = *(const bf16x8*)(QrowA + hi * 8);
  const bf16x8 qa1 = *(const bf16x8*)(QrowA + 16 + hi * 8);
  const bf16x8 qb0 = *(const bf16x8*)(QrowB + hi * 8);
  const bf16x8 qb1 = *(const bf16x8*)(QrowB + 16 + hi * 8);
  f32x16 zro;
#pragma unroll
  for (int i = 0; i < 16; ++i) zro[i] = 0.f;
  f32x16 accA = zro, accB = zro;
  float lsA[4] = {0.f, 0.f, 0.f, 0.f};
  float lsB[4] = {0.f, 0.f, 0.f, 0.f};
  const int kgd = tid >> 6, kkv = tid & 63;        // K: granule (kgd*128 + kkv)
  const int vdv = tid & 31, vgk = tid >> 5;        // V: granule (vgk*32 + vdv)
  const short* kvsrc = Kb + (size_t)kkv * HD + kgd * 8;
  const short* vvsrc = Vb + (size_t)vdv * SS + vgk * 8;
  short* kdst0 = sK + ((size_t)kgd * 128 + kkv) * 8;
  short* kdst1 = kdst0 + 64 * 8;                   // kv + 64
  short* vdst0 = sV + ((size_t)vgk * 32 + vdv) * 8;
  short* vdst1 = vdst0 + 8 * 32 * 8;               // gkv + 8
  bf16x8 stgK0 = *(const bf16x8*)kvsrc;
  bf16x8 stgK1 = *(const bf16x8*)(kvsrc + 64 * HD);
  bf16x8 stgV0 = *(const bf16x8*)vvsrc;
  bf16x8 stgV1 = *(const bf16x8*)(vvsrc + 64);

  auto pack = [&](const f32x16& p, bf16x8& A, bf16x8& B) {
    unsigned a0 = cvtpk(p[0], p[1]),   a1 = cvtpk(p[2], p[3]);
    unsigned b0 = cvtpk(p[4], p[5]),   b1 = cvtpk(p[6], p[7]);
    plswap(a0, b0); plswap(a1, b1);
    unsigned c0 = cvtpk(p[8], p[9]),   c1 = cvtpk(p[10], p[11]);
    unsigned d0 = cvtpk(p[12], p[13]), d1 = cvtpk(p[14], p[15]);
    plswap(c0, d0); plswap(c1, d1);
    union { unsigned u[4]; bf16x8 v; } x, y;
    x.u[0] = a0; x.u[1] = a1; x.u[2] = b0; x.u[3] = b1;   // kv +0..15
    y.u[0] = c0; y.u[1] = c1; y.u[2] = d0; y.u[3] = d1;   // kv +16..31
    A = x.v; B = y.v;
  };

  for (int kt = 0; kt < NIT; ++kt) {
    __syncthreads();
    *(bf16x8*)kdst0 = stgK0;
    *(bf16x8*)kdst1 = stgK1;
    *(bf16x8*)vdst0 = stgV0;
    *(bf16x8*)vdst1 = stgV1;
    __syncthreads();
    if (kt + 1 < NIT) {
      const short* ks = kvsrc + (size_t)(kt + 1) * 128 * HD;
      stgK0 = *(const bf16x8*)ks;
      stgK1 = *(const bf16x8*)(ks + 64 * HD);
      const short* vs = vvsrc + (kt + 1) * 128;
      stgV0 = *(const bf16x8*)vs;
      stgV1 = *(const bf16x8*)(vs + 64);
    }
#pragma unroll
    for (int sub = 0; sub < 2; ++sub) {
      const int kb = sub * 64;
      const bf16x8 a00 = *(const bf16x8*)(sK + ((hi)*128 + kb + l31) * 8);
      const bf16x8 a01 = *(const bf16x8*)(sK + ((2 + hi) * 128 + kb + l31) * 8);
      const bf16x8 a10 = *(const bf16x8*)(sK + ((hi)*128 + kb + 32 + l31) * 8);
      const bf16x8 a11 = *(const bf16x8*)(sK + ((2 + hi) * 128 + kb + 32 + l31) * 8);
      const bf16x8 vb0 = *(const bf16x8*)(sV + ((sub * 8 + hi) * 32 + l31) * 8);
      const bf16x8 vb1 = *(const bf16x8*)(sV + ((sub * 8 + 2 + hi) * 32 + l31) * 8);
      const bf16x8 vb2 = *(const bf16x8*)(sV + ((sub * 8 + 4 + hi) * 32 + l31) * 8);
      const bf16x8 vb3 = *(const bf16x8*)(sV + ((sub * 8 + 6 + hi) * 32 + l31) * 8);
      // scores for both independent q-streams (zero C-init; no bias)
      __builtin_amdgcn_s_setprio(1);
      f32x16 sA0 = __builtin_amdgcn_mfma_f32_32x32x16_bf16(a00, qa0, zro, 0, 0, 0);
      sA0 = __builtin_amdgcn_mfma_f32_32x32x16_bf16(a01, qa1, sA0, 0, 0, 0);
      f32x16 sA1 = __builtin_amdgcn_mfma_f32_32x32x16_bf16(a10, qa0, zro, 0, 0, 0);
      sA1 = __builtin_amdgcn_mfma_f32_32x32x16_bf16(a11, qa1, sA1, 0, 0, 0);
      f32x16 sB0 = __builtin_amdgcn_mfma_f32_32x32x16_bf16(a00, qb0, zro, 0, 0, 0);
      sB0 = __builtin_amdgcn_mfma_f32_32x32x16_bf16(a01, qb1, sB0, 0, 0, 0);
      f32x16 sB1 = __builtin_amdgcn_mfma_f32_32x32x16_bf16(a10, qb0, zro, 0, 0, 0);
      sB1 = __builtin_amdgcn_mfma_f32_32x32x16_bf16(a11, qb1, sB1, 0, 0, 0);
      __builtin_amdgcn_s_setprio(0);
      // stream A softmax + PV
      f32x16 p;
#pragma unroll
      for (int r = 0; r < 16; ++r) { p[r] = exp2_(sA0[r]); lsA[r & 3] += p[r]; }
      bf16x8 pa1, pa2;
      pack(p, pa1, pa2);
#pragma unroll
      for (int r = 0; r < 16; ++r) { p[r] = exp2_(sA1[r]); lsA[r & 3] += p[r]; }
      bf16x8 pa3, pa4;
      pack(p, pa3, pa4);
      __builtin_amdgcn_s_setprio(1);
      accA = __builtin_amdgcn_mfma_f32_32x32x16_bf16(pa1, vb0, accA, 0, 0, 0);
      accA = __builtin_amdgcn_mfma_f32_32x32x16_bf16(pa2, vb1, accA, 0, 0, 0);
      accA = __builtin_amdgcn_mfma_f32_32x32x16_bf16(pa3, vb2, accA, 0, 0, 0);
      accA = __builtin_amdgcn_mfma_f32_32x32x16_bf16(pa4, vb3, accA, 0, 0, 0);
      __builtin_amdgcn_s_setprio(0);
      // stream B softmax + PV
#pragma unroll
      for (int r = 0; r < 16; ++r) { p[r] = exp2_(sB0[r]); lsB[r & 3] += p[r]; }
      bf16x8 pb1, pb2;
      pack(p, pb1, pb2);
#pragma unroll
      for (int r = 0; r < 16; ++r) { p[r] = exp2_(sB1[r]); lsB[r & 3] += p[r]; }
      bf16x8 pb3, pb4;
      pack(p, pb3, pb4);
      __builtin_amdgcn_s_setprio(1);
      accB = __builtin_amdgcn_mfma_f32_32x32x16_bf16(pb1, vb0, accB, 0, 0, 0);
      accB = __builtin_amdgcn_mfma_f32_32x32x16_bf16(pb2, vb1, accB, 0, 0, 0);
      accB = __builtin_amdgcn_mfma_f32_32x32x16_bf16(pb3, vb2, accB, 0, 0, 0);
      accB = __builtin_amdgcn_mfma_f32_32x32x16_bf16(pb4, vb3, accB, 0, 0, 0);
      __builtin_amdgcn_s_setprio(0);
    }
  }
  float fsA = (lsA[0] + lsA[1]) + (lsA[2] + lsA[3]);
  float fsB = (lsB[0] + lsB[1]) + (lsB[2] + lsB[3]);
  fsA += __shfl_xor(fsA, 32);
  fsB += __shfl_xor(fsB, 32);
  short* OP = half ? OP1 : OP0;
#pragma unroll
  for (int r = 0; r < 16; ++r) {
    int qq = (r & 3) + 8 * (r >> 2) + 4 * hi;
    int mA = b * SS + qbase + qq;
    OP[(size_t)mA * SH + h * HD + l31] = f2bf(accA[r]);
    int mB = mA + 32;
    OP[(size_t)mB * SH + h * HD + l31] = f2bf(accB[r]);
    float lvA = bperm_f(qq, fsA);
    float lvB = bperm_f(qq, fsB);
    if (l31 == 0) {
      Lp[((size_t)half * 16 + bh) * SS + qbase + qq] = lvA;
      Lp[((size_t)half * 16 + bh) * SS + qbase + 32 + qq] = lvB;
    }
  }
}

// ---- host ----
extern "C" void kernel_launch(void* const* d_in, const int* in_sizes, int n_in,
                              void* d_out, int out_size, void* d_ws, size_t ws_size,
                              hipStream_t stream) {
  (void)in_sizes; (void)n_in; (void)out_size;
  if (ws_size < WS_NEED) return;
  const float* x  = (const float*)d_in[0];
  const unsigned char* mask = (const unsigned char*)d_in[1];
  const float* wq = (const float*)d_in[2];
  const float* bq = (const float*)d_in[3];
  const float* wk = (const float*)d_in[4];
  const float* bk = (const float*)d_in[5];
  const float* wv = (const float*)d_in[6];
  const float* bv = (const float*)d_in[7];
  const float* wo = (const float*)d_in[8];
  const float* bo = (const float*)d_in[9];
  char* ws = (char*)d_ws;
  int*   cnts    = (int*)(ws + OFF_CNT);
  short* xb      = (short*)(ws + OFF_XB);
  short* Wqkv    = (short*)(ws + OFF_WQKV);
  float* bqkv    = (float*)(ws + OFF_BQKV);
  short* wob     = (short*)(ws + OFF_WOB);
  float* bof     = (float*)(ws + OFF_BO);
  short* Qw      = (short*)(ws + OFF_Q);
  short* Kw      = (short*)(ws + OFF_K);
  short* Vw      = (short*)(ws + OFF_V);
  short* Vtw     = (short*)(ws + OFF_VT);
  // overlays (lifetimes verified):
  short* Kc      = (short*)(ws + OFF_XB);             // xb dead after gemm<0>
  short* OP0     = (short*)(ws + OFF_K);              // K dead after gather
  short* OP1     = (short*)(ws + OFF_V);              // V dead after gather
  float* Lp      = (float*)(ws + OFF_O);              // written by attn only
  // idxC: written by prep_scan (blocks 0-1), read by gather, dead after.
  int* idxSafe = (int*)(ws + OFF_O);

  prep_scan_kernel<<<1155, 256, 0, stream>>>(x, wq, bq, wk, bk, wv, bv, wo, bo,
                                             xb, Wqkv, bqkv, wob, bof,
                                             mask, idxSafe, cnts);
  gemm_kernel<0><<<dim3(128, 12), 256, 0, stream>>>(xb, Wqkv, bqkv, Qw, Kw, Vw,
                                                    nullptr, nullptr, nullptr, nullptr);
  gather_kv_kernel<<<dim3(64, 16), 256, 0, stream>>>(Kw, Vw, idxSafe, cnts, Kc, Vtw);
  attn_kernel<<<dim3(16, 16, 2), 256, 0, stream>>>(Qw, Kc, Vtw, cnts, OP0, OP1, Lp);
  gemm_kernel<1><<<dim3(128, 4), 256, 0, stream>>>(OP0, wob, bof,
                                                   nullptr, nullptr, nullptr, (float*)d_out,
                                                   OP1, Lp, cnts);
}

// Round 16
// 78.527 us; speedup vs baseline: 1.0107x; 1.0107x over previous
//
#include <hip/hip_runtime.h>

#define DEV __device__ __forceinline__

typedef __attribute__((ext_vector_type(8)))  short bf16x8;
typedef __attribute__((ext_vector_type(4)))  short s16x4;
typedef __attribute__((ext_vector_type(16))) float f32x16;

constexpr int SB = 2;            // batch
constexpr int SS = 4096;         // seq len
constexpr int SH = 256;          // hidden
constexpr int NHEAD = 8, HD = 32;
constexpr int M_TOK = SB * SS;   // 8192 token rows
constexpr int NQKV = 3 * SH;     // 768

// ---- workspace layout (bytes) ----
constexpr size_t OFF_CNT  = 0;                                 // int[4]: pad cnt, real cnt
constexpr size_t OFF_BIAS = 256;                               // spare
constexpr size_t OFF_XB   = OFF_BIAS + 32768;                  // bf16[8192*256]; later Kc
constexpr size_t OFF_WQKV = OFF_XB + (size_t)M_TOK * SH * 2;   // bf16[768*256]
constexpr size_t OFF_BQKV = OFF_WQKV + (size_t)NQKV * SH * 2;  // f32[768] (pad 4096)
constexpr size_t OFF_WOB  = OFF_BQKV + 4096;                   // bf16[256*256]
constexpr size_t OFF_BO   = OFF_WOB + (size_t)SH * SH * 2;     // f32[256] (pad 1024)
constexpr size_t OFF_Q    = OFF_BO + 1024;                     // bf16 [16][4096][32]
constexpr size_t OFF_K    = OFF_Q + (size_t)M_TOK * SH * 2;    // K; later OP0
constexpr size_t OFF_V    = OFF_K + (size_t)M_TOK * SH * 2;    // V row-major; later OP1
constexpr size_t OFF_VT   = OFF_V + (size_t)M_TOK * SH * 2;    // bf16 [16][32][4096] (compacted)
constexpr size_t OFF_O    = OFF_VT + (size_t)M_TOK * SH * 2;   // idxC (32KB) then f32 Lp[2][16][4096]
constexpr size_t WS_NEED  = OFF_O + (size_t)M_TOK * SH * 2;

// ---- helpers ----
DEV short f2bf(float f) {                      // RNE f32 -> bf16 bits
  unsigned u = __builtin_bit_cast(unsigned, f);
  u = (u + 0x7FFFu + ((u >> 16) & 1u)) >> 16;
  return (short)u;
}

DEV float bf2f(short s) {
  return __builtin_bit_cast(float, ((unsigned)(unsigned short)s) << 16);
}

DEV float exp2_(float x) {                     // trans-pipe exp2
#if __has_builtin(__builtin_amdgcn_exp2f)
  return __builtin_amdgcn_exp2f(x);
#else
  float r;
  asm("v_exp_f32 %0, %1\n\ts_nop 0" : "=v"(r) : "v"(x));
  return r;
#endif
}

DEV float rcp_(float x) {                      // approx 1/x (rel err ~1e-7)
#if __has_builtin(__builtin_amdgcn_rcpf)
  return __builtin_amdgcn_rcpf(x);
#else
  float r;
  asm("v_rcp_f32 %0, %1\n\ts_nop 0" : "=v"(r) : "v"(x));
  return r;
#endif
}

DEV unsigned cvtpk(float lo, float hi) {       // {bf16(lo), bf16(hi)} packed
  unsigned r;
  asm("v_cvt_pk_bf16_f32 %0, %1, %2" : "=v"(r) : "v"(lo), "v"(hi));
  return r;
}

DEV void plswap(unsigned& a, unsigned& b) {    // v_permlane32_swap_b32 a, b
  asm("v_permlane32_swap_b32 %0, %1" : "+v"(a), "+v"(b));
}

DEV float bperm_f(int srclane, float v) {
  int r = __builtin_amdgcn_ds_bpermute(srclane * 4, __builtin_bit_cast(int, v));
  return __builtin_bit_cast(float, r);
}

// ---- 1. fused prep + mask-scan (verified round 12) ----
__global__ void prep_scan_kernel(const float* __restrict__ x,
    const float* __restrict__ wq, const float* __restrict__ bq,
    const float* __restrict__ wk, const float* __restrict__ bk,
    const float* __restrict__ wv, const float* __restrict__ bv,
    const float* __restrict__ wo, const float* __restrict__ bo,
    short* __restrict__ xb, short* __restrict__ Wqkv, float* __restrict__ bqkv,
    short* __restrict__ wob, float* __restrict__ bof,
    const unsigned char* __restrict__ m, int* __restrict__ idxC,
    int* __restrict__ cnts) {
  const int tid = threadIdx.x;
  if (blockIdx.x < 2) {
    __shared__ int f_mis, f_off4, f_3f;
    __shared__ int ts[256];
    const int b = blockIdx.x;
    if (tid == 0) { f_mis = 0; f_off4 = 0; f_3f = 0; }
    __syncthreads();
    int lm = 0, lo4 = 0, l3f = 0;
    for (int i = tid; i < 8192; i += 256) {
      unsigned char c = m[i];
      if (c) {
        if (i & 3) lm = 1;
        if ((i & 7) == 4) lo4 = 1;
        if ((i & 3) == 3 && c == 0x3F) l3f = 1;
      }
    }
    if (lm)  atomicOr(&f_mis, 1);
    if (lo4) atomicOr(&f_off4, 1);
    if (l3f) atomicOr(&f_3f, 1);
    __syncthreads();
    const int f = !f_mis ? (f_off4 ? 1 : 3) : (f_3f ? 2 : 0);  // 0=u8 1=i32 2=f32 3=i64
    int bits = 0;
    const int rbase = b * 4096 + tid * 16;
#pragma unroll
    for (int j = 0; j < 16; ++j) {
      int r = rbase + j;
      bool on;
      if (f == 0)      on = m[r] != 0;
      else if (f == 1) on = m[(size_t)r * 4] != 0;
      else if (f == 2) on = m[(size_t)r * 4 + 3] != 0;
      else             on = m[(size_t)r * 8] != 0;
      bits |= (int)on << j;
    }
    const int cnt = __popc(bits);
    ts[tid] = cnt;
    __syncthreads();
    for (int off = 1; off < 256; off <<= 1) {
      int u = (tid >= off) ? ts[tid - off] : 0;
      __syncthreads();
      ts[tid] += u;
      __syncthreads();
    }
    const int total = ts[255];
    int pos = ts[tid] - cnt;   // exclusive
    int* idxB = idxC + b * 4096;
    if (total == 0) {
      for (int j = tid; j < 4096; j += 256) idxB[j] = j;
      if (tid == 0) { cnts[b] = 4096; cnts[2 + b] = 4096; }
      return;
    }
#pragma unroll
    for (int j = 0; j < 16; ++j)
      if ((bits >> j) & 1) { idxB[pos] = tid * 16 + j; ++pos; }
    int cntpad = (total + 255) & ~255;
    if (cntpad < 256) cntpad = 256;
    for (int j = total + tid; j < cntpad; j += 256) idxB[j] = -1;
    if (tid == 0) { cnts[b] = cntpad; cnts[2 + b] = total; }
    return;
  }
  const float QS = (float)(1.4426950408889634 / 5.656854249492381);  // log2(e)/sqrt(32)
  long i = ((long)(blockIdx.x - 2) * 256 + tid) * 8;
  const long NX = (long)M_TOK * SH;
  const long NW = (long)NQKV * SH;
  if (i < NX) {
    const float4* s = (const float4*)(x + i);
    float4 f0 = s[0], f1 = s[1];
    bf16x8 o;
    o[0]=f2bf(f0.x); o[1]=f2bf(f0.y); o[2]=f2bf(f0.z); o[3]=f2bf(f0.w);
    o[4]=f2bf(f1.x); o[5]=f2bf(f1.y); o[6]=f2bf(f1.z); o[7]=f2bf(f1.w);
    *(bf16x8*)(xb + i) = o;
    return;
  }
  i -= NX;
  if (i < NW) {
    int n = (int)(i >> 8), kk = (int)(i & 255);
    int tn = n >> 8, rr = n & 255;
    const float* src = (tn == 0 ? wq : (tn == 1 ? wk : wv)) + rr * 256 + kk;
    float sc = tn == 0 ? QS : 1.f;
    float4 f0 = *(const float4*)src, f1 = *(const float4*)(src + 4);
    bf16x8 o;
    o[0]=f2bf(f0.x*sc); o[1]=f2bf(f0.y*sc); o[2]=f2bf(f0.z*sc); o[3]=f2bf(f0.w*sc);
    o[4]=f2bf(f1.x*sc); o[5]=f2bf(f1.y*sc); o[6]=f2bf(f1.z*sc); o[7]=f2bf(f1.w*sc);
    *(bf16x8*)(Wqkv + i) = o;
    return;
  }
  i -= NW;
  if (i < NQKV) {
    int n = (int)i;
#pragma unroll
    for (int j = 0; j < 8; ++j) {
      int nn = n + j, tn = nn >> 8, rr = nn & 255;
      const float* src = tn == 0 ? bq : (tn == 1 ? bk : bv);
      bqkv[nn] = src[rr] * (tn == 0 ? QS : 1.f);
    }
    return;
  }
  i -= NQKV;
  if (i < (long)SH * SH) {
    const float4* s = (const float4*)(wo + i);
    float4 f0 = s[0], f1 = s[1];
    bf16x8 o;
    o[0]=f2bf(f0.x); o[1]=f2bf(f0.y); o[2]=f2bf(f0.z); o[3]=f2bf(f0.w);
    o[4]=f2bf(f1.x); o[5]=f2bf(f1.y); o[6]=f2bf(f1.z); o[7]=f2bf(f1.w);
    *(bf16x8*)(wob + i) = o;
    return;
  }
  i -= (long)SH * SH;
  if (i < SH) {
#pragma unroll
    for (int j = 0; j < 8; ++j) bof[i + j] = bo[i + j];
  }
}

// ---- 2/5. GEMM 128x64 tile, BK=64 (ROUND-12 VERIFIED register staging) ----
// MODE 1 fuses split-combine into A staging.
template <int MODE>
__global__ __launch_bounds__(256) void gemm_kernel(
    const short* __restrict__ Ag, const short* __restrict__ Bg,
    const float* __restrict__ bias,
    short* __restrict__ q, short* __restrict__ k, short* __restrict__ v,
    float* __restrict__ outf,
    const short* __restrict__ P1, const float* __restrict__ Lp,
    const int* __restrict__ cnts) {
  __shared__ __align__(16) short lA[8192];   // granule-major [kg 0..7][m 0..127] x8
  __shared__ __align__(16) short lB[4096];   // [kg 0..7][n 0..63] x8
  const int tid = threadIdx.x;
  const int lane = tid & 63, w = tid >> 6;
  const int wm = w >> 1, wn = w & 1;
  const int hi = lane >> 5, l31 = lane & 31;
  const int mb = blockIdx.x, nb = blockIdx.y;
  f32x16 acc0, acc1;
#pragma unroll
  for (int i = 0; i < 16; ++i) { acc0[i] = 0.f; acc1[i] = 0.f; }
  float npadv[2] = {0.f, 0.f};
  if constexpr (MODE == 1) {
    npadv[0] = (float)(cnts[0] - cnts[2]);
    npadv[1] = (float)(cnts[1] - cnts[3]);
  }
  bf16x8 ra[4], rb[2];
  const int am = tid >> 3, ak = tid & 7;
  auto gload = [&](int kb) {
#pragma unroll
    for (int p = 0; p < 4; ++p) {
      if constexpr (MODE == 0) {
        ra[p] = *(const bf16x8*)(Ag + (size_t)(mb * 128 + p * 32 + am) * 256 + kb * 64 + ak * 8);
      } else {
        const int row = mb * 128 + p * 32 + am;
        const int bb = row >> 12, ss = row & 4095;
        const int colb = kb * 64 + ak * 8;
        const int bhh = bb * 8 + (colb >> 5);
        float l = Lp[(size_t)bhh * SS + ss] + Lp[(size_t)(16 + bhh) * SS + ss] - npadv[bb];
        float rc = rcp_(l);
        bf16x8 o0 = *(const bf16x8*)(Ag + (size_t)row * 256 + colb);
        bf16x8 o1 = *(const bf16x8*)(P1 + (size_t)row * 256 + colb);
        bf16x8 o;
#pragma unroll
        for (int j = 0; j < 8; ++j) o[j] = f2bf((bf2f(o0[j]) + bf2f(o1[j])) * rc);
        ra[p] = o;
      }
    }
#pragma unroll
    for (int p = 0; p < 2; ++p)
      rb[p] = *(const bf16x8*)(Bg + (size_t)(nb * 64 + p * 32 + am) * 256 + kb * 64 + ak * 8);
  };
  gload(0);
  for (int kb = 0; kb < 4; ++kb) {
    __syncthreads();
#pragma unroll
    for (int p = 0; p < 4; ++p)
      *(bf16x8*)(lA + (ak * 128 + p * 32 + am) * 8) = ra[p];
#pragma unroll
    for (int p = 0; p < 2; ++p)
      *(bf16x8*)(lB + (ak * 64 + p * 32 + am) * 8) = rb[p];
    __syncthreads();
    if (kb < 3) gload(kb + 1);
#pragma unroll
    for (int ks = 0; ks < 4; ++ks) {
      bf16x8 af0 = *(const bf16x8*)(lA + ((2 * ks + hi) * 128 + wm * 64 + l31) * 8);
      bf16x8 af1 = *(const bf16x8*)(lA + ((2 * ks + hi) * 128 + wm * 64 + 32 + l31) * 8);
      bf16x8 bf  = *(const bf16x8*)(lB + ((2 * ks + hi) * 64 + wn * 32 + l31) * 8);
      acc0 = __builtin_amdgcn_mfma_f32_32x32x16_bf16(af0, bf, acc0, 0, 0, 0);
      acc1 = __builtin_amdgcn_mfma_f32_32x32x16_bf16(af1, bf, acc1, 0, 0, 0);
    }
  }
  const int ncol = nb * 64 + wn * 32 + l31;
  const float bval = bias[ncol];
  if (MODE == 0) {
    const int tensor = nb >> 2;                       // 0=Q 1=K 2=V
    short* dst = tensor == 0 ? q : (tensor == 1 ? k : v);
    const int a = (nb & 3) * 64 + wn * 32 + l31;
    const int hh = a >> 5, d = a & 31;
#pragma unroll
    for (int mt = 0; mt < 2; ++mt) {
      const f32x16& acc = mt == 0 ? acc0 : acc1;
#pragma unroll
      for (int r = 0; r < 16; ++r) {
        int gm = mb * 128 + wm * 64 + mt * 32 + (r & 3) + 8 * (r >> 2) + 4 * hi;
        int bb = gm >> 12, ss = gm & 4095;
        dst[(((size_t)bb * NHEAD + hh) * SS + ss) * HD + d] = f2bf(acc[r] + bval);
      }
    }
  } else {
#pragma unroll
    for (int mt = 0; mt < 2; ++mt) {
      const f32x16& acc = mt == 0 ? acc0 : acc1;
#pragma unroll
      for (int r = 0; r < 16; ++r) {
        int gm = mb * 128 + wm * 64 + mt * 32 + (r & 3) + 8 * (r >> 2) + 4 * hi;
        outf[(size_t)gm * SH + ncol] = acc[r] + bval;
      }
    }
  }
}

// ---- 3. fused gather-K + gather-transpose-V (pad rows = 0) ----
__global__ __launch_bounds__(256) void gather_kv_kernel(const short* __restrict__ K,
    const short* __restrict__ V, const int* __restrict__ idxC, const int* __restrict__ cnts,
    short* __restrict__ Kc, short* __restrict__ Vt) {
  const int bh = blockIdx.y, b = bh >> 3;
  const int jb = blockIdx.x * 64;
  if (jb >= cnts[b]) return;
  __shared__ short t[64][33];
  const int tid = threadIdx.x;
  const int s = tid >> 2, g = tid & 3;
  const int ix = idxC[b * 4096 + jb + s];
  bf16x8 kvv{}, vvv{};
  if (ix >= 0) {
    kvv = *(const bf16x8*)(K + ((size_t)bh * SS + ix) * HD + g * 8);
    vvv = *(const bf16x8*)(V + ((size_t)bh * SS + ix) * HD + g * 8);
  }
  *(bf16x8*)(Kc + ((size_t)bh * SS + jb + s) * HD + g * 8) = kvv;
#pragma unroll
  for (int j = 0; j < 8; ++j) t[s][g * 8 + j] = vvv[j];
  __syncthreads();
  const int d = tid >> 3, gs = tid & 7;
  bf16x8 out;
#pragma unroll
  for (int j = 0; j < 8; ++j) out[j] = t[gs * 8 + j][d];
  *(bf16x8*)(Vt + ((size_t)bh * HD + d) * SS + jb + gs * 8) = out;
}

// ---- 4. flash attention, split x2, KVBLK=128, dual q-stream, scalar lsum,
//         s_setprio around MFMA clusters (round-14 verified) ----
__global__ __launch_bounds__(256, 2) void attn_kernel(const short* __restrict__ Q,
    const short* __restrict__ Kc, const short* __restrict__ Vt,
    const int* __restrict__ cnts,
    short* __restrict__ OP0, short* __restrict__ OP1, float* __restrict__ Lp) {
  __shared__ __align__(16) short sK[4096];   // [gd 0..3][kv 0..127] x8
  __shared__ __align__(16) short sV[4096];   // [gkv 0..15][d 0..31] x8
  const int tid = threadIdx.x;
  const int lane = tid & 63, wave = tid >> 6;
  const int hi = lane >> 5, l31 = lane & 31;
  const int qblk = blockIdx.x, bh = blockIdx.y, half = blockIdx.z;
  const int b = bh >> 3, h = bh & 7;
  const int Lh = cnts[b] >> 1;          // multiple of 128
  const int NIT = Lh >> 7;
  const int kv0 = half * Lh;
  const short* Kb = Kc + ((size_t)bh * SS + kv0) * HD;
  const short* Vb = Vt + (size_t)bh * HD * SS + kv0;
  const int qbase = qblk * 256 + wave * 64;     // this wave: q rows [qbase, qbase+64)
  const short* QrowA = Q + ((size_t)bh * SS + qbase + l31) * HD;
  const short* QrowB = QrowA + 32 * HD;
  const bf16x8 qa0 = *(const bf16x8*)(QrowA + hi * 8);
  const bf16x8 qa1 = *(const bf16x8*)(QrowA + 16 + hi * 8);
  const bf16x8 qb0 = *(const bf16x8*)(QrowB + hi * 8);
  const bf16x8 qb1 = *(const bf16x8*)(QrowB + 16 + hi * 8);
  f32x16 zro;
#pragma unroll
  for (int i = 0; i < 16; ++i) zro[i] = 0.f;
  f32x16 accA = zro, accB = zro;
  float lsA[4] = {0.f, 0.f, 0.f, 0.f};
  float lsB[4] = {0.f, 0.f, 0.f, 0.f};
  const int kgd = tid >> 6, kkv = tid & 63;        // K: granule (kgd*128 + kkv)
  const int vdv = tid & 31, vgk = tid >> 5;        // V: granule (vgk*32 + vdv)
  const short* kvsrc = Kb + (size_t)kkv * HD + kgd * 8;
  const short* vvsrc = Vb + (size_t)vdv * SS + vgk * 8;
  short* kdst0 = sK + ((size_t)kgd * 128 + kkv) * 8;
  short* kdst1 = kdst0 + 64 * 8;                   // kv + 64
  short* vdst0 = sV + ((size_t)vgk * 32 + vdv) * 8;
  short* vdst1 = vdst0 + 8 * 32 * 8;               // gkv + 8
  bf16x8 stgK0 = *(const bf16x8*)kvsrc;
  bf16x8 stgK1 = *(const bf16x8*)(kvsrc + 64 * HD);
  bf16x8 stgV0 = *(const bf16x8*)vvsrc;
  bf16x8 stgV1 = *(const bf16x8*)(vvsrc + 64);

  auto pack = [&](const f32x16& p, bf16x8& A, bf16x8& B) {
    unsigned a0 = cvtpk(p[0], p[1]),   a1 = cvtpk(p[2], p[3]);
    unsigned b0 = cvtpk(p[4], p[5]),   b1 = cvtpk(p[6], p[7]);
    plswap(a0, b0); plswap(a1, b1);
    unsigned c0 = cvtpk(p[8], p[9]),   c1 = cvtpk(p[10], p[11]);
    unsigned d0 = cvtpk(p[12], p[13]), d1 = cvtpk(p[14], p[15]);
    plswap(c0, d0); plswap(c1, d1);
    union { unsigned u[4]; bf16x8 v; } x, y;
    x.u[0] = a0; x.u[1] = a1; x.u[2] = b0; x.u[3] = b1;   // kv +0..15
    y.u[0] = c0; y.u[1] = c1; y.u[2] = d0; y.u[3] = d1;   // kv +16..31
    A = x.v; B = y.v;
  };

  for (int kt = 0; kt < NIT; ++kt) {
    __syncthreads();
    *(bf16x8*)kdst0 = stgK0;
    *(bf16x8*)kdst1 = stgK1;
    *(bf16x8*)vdst0 = stgV0;
    *(bf16x8*)vdst1 = stgV1;
    __syncthreads();
    if (kt + 1 < NIT) {
      const short* ks = kvsrc + (size_t)(kt + 1) * 128 * HD;
      stgK0 = *(const bf16x8*)ks;
      stgK1 = *(const bf16x8*)(ks + 64 * HD);
      const short* vs = vvsrc + (kt + 1) * 128;
      stgV0 = *(const bf16x8*)vs;
      stgV1 = *(const bf16x8*)(vs + 64);
    }
#pragma unroll
    for (int sub = 0; sub < 2; ++sub) {
      const int kb = sub * 64;
      const bf16x8 a00 = *(const bf16x8*)(sK + ((hi)*128 + kb + l31) * 8);
      const bf16x8 a01 = *(const bf16x8*)(sK + ((2 + hi) * 128 + kb + l31) * 8);
      const bf16x8 a10 = *(const bf16x8*)(sK + ((hi)*128 + kb + 32 + l31) * 8);
      const bf16x8 a11 = *(const bf16x8*)(sK + ((2 + hi) * 128 + kb + 32 + l31) * 8);
      const bf16x8 vb0 = *(const bf16x8*)(sV + ((sub * 8 + hi) * 32 + l31) * 8);
      const bf16x8 vb1 = *(const bf16x8*)(sV + ((sub * 8 + 2 + hi) * 32 + l31) * 8);
      const bf16x8 vb2 = *(const bf16x8*)(sV + ((sub * 8 + 4 + hi) * 32 + l31) * 8);
      const bf16x8 vb3 = *(const bf16x8*)(sV + ((sub * 8 + 6 + hi) * 32 + l31) * 8);
      // scores for both independent q-streams (zero C-init; no bias)
      __builtin_amdgcn_s_setprio(1);
      f32x16 sA0 = __builtin_amdgcn_mfma_f32_32x32x16_bf16(a00, qa0, zro, 0, 0, 0);
      sA0 = __builtin_amdgcn_mfma_f32_32x32x16_bf16(a01, qa1, sA0, 0, 0, 0);
      f32x16 sA1 = __builtin_amdgcn_mfma_f32_32x32x16_bf16(a10, qa0, zro, 0, 0, 0);
      sA1 = __builtin_amdgcn_mfma_f32_32x32x16_bf16(a11, qa1, sA1, 0, 0, 0);
      f32x16 sB0 = __builtin_amdgcn_mfma_f32_32x32x16_bf16(a00, qb0, zro, 0, 0, 0);
      sB0 = __builtin_amdgcn_mfma_f32_32x32x16_bf16(a01, qb1, sB0, 0, 0, 0);
      f32x16 sB1 = __builtin_amdgcn_mfma_f32_32x32x16_bf16(a10, qb0, zro, 0, 0, 0);
      sB1 = __builtin_amdgcn_mfma_f32_32x32x16_bf16(a11, qb1, sB1, 0, 0, 0);
      __builtin_amdgcn_s_setprio(0);
      // stream A softmax + PV
      f32x16 p;
#pragma unroll
      for (int r = 0; r < 16; ++r) { p[r] = exp2_(sA0[r]); lsA[r & 3] += p[r]; }
      bf16x8 pa1, pa2;
      pack(p, pa1, pa2);
#pragma unroll
      for (int r = 0; r < 16; ++r) { p[r] = exp2_(sA1[r]); lsA[r & 3] += p[r]; }
      bf16x8 pa3, pa4;
      pack(p, pa3, pa4);
      __builtin_amdgcn_s_setprio(1);
      accA = __builtin_amdgcn_mfma_f32_32x32x16_bf16(pa1, vb0, accA, 0, 0, 0);
      accA = __builtin_amdgcn_mfma_f32_32x32x16_bf16(pa2, vb1, accA, 0, 0, 0);
      accA = __builtin_amdgcn_mfma_f32_32x32x16_bf16(pa3, vb2, accA, 0, 0, 0);
      accA = __builtin_amdgcn_mfma_f32_32x32x16_bf16(pa4, vb3, accA, 0, 0, 0);
      __builtin_amdgcn_s_setprio(0);
      // stream B softmax + PV
#pragma unroll
      for (int r = 0; r < 16; ++r) { p[r] = exp2_(sB0[r]); lsB[r & 3] += p[r]; }
      bf16x8 pb1, pb2;
      pack(p, pb1, pb2);
#pragma unroll
      for (int r = 0; r < 16; ++r) { p[r] = exp2_(sB1[r]); lsB[r & 3] += p[r]; }
      bf16x8 pb3, pb4;
      pack(p, pb3, pb4);
      __builtin_amdgcn_s_setprio(1);
      accB = __builtin_amdgcn_mfma_f32_32x32x16_bf16(pb1, vb0, accB, 0, 0, 0);
      accB = __builtin_amdgcn_mfma_f32_32x32x16_bf16(pb2, vb1, accB, 0, 0, 0);
      accB = __builtin_amdgcn_mfma_f32_32x32x16_bf16(pb3, vb2, accB, 0, 0, 0);
      accB = __builtin_amdgcn_mfma_f32_32x32x16_bf16(pb4, vb3, accB, 0, 0, 0);
      __builtin_amdgcn_s_setprio(0);
    }
  }
  float fsA = (lsA[0] + lsA[1]) + (lsA[2] + lsA[3]);
  float fsB = (lsB[0] + lsB[1]) + (lsB[2] + lsB[3]);
  fsA += __shfl_xor(fsA, 32);
  fsB += __shfl_xor(fsB, 32);
  short* OP = half ? OP1 : OP0;
#pragma unroll
  for (int r = 0; r < 16; ++r) {
    int qq = (r & 3) + 8 * (r >> 2) + 4 * hi;
    int mA = b * SS + qbase + qq;
    OP[(size_t)mA * SH + h * HD + l31] = f2bf(accA[r]);
    int mB = mA + 32;
    OP[(size_t)mB * SH + h * HD + l31] = f2bf(accB[r]);
    float lvA = bperm_f(qq, fsA);
    float lvB = bperm_f(qq, fsB);
    if (l31 == 0) {
      Lp[((size_t)half * 16 + bh) * SS + qbase + qq] = lvA;
      Lp[((size_t)half * 16 + bh) * SS + qbase + 32 + qq] = lvB;
    }
  }
}

// ---- host ----
extern "C" void kernel_launch(void* const* d_in, const int* in_sizes, int n_in,
                              void* d_out, int out_size, void* d_ws, size_t ws_size,
                              hipStream_t stream) {
  (void)in_sizes; (void)n_in; (void)out_size;
  if (ws_size < WS_NEED) return;
  const float* x  = (const float*)d_in[0];
  const unsigned char* mask = (const unsigned char*)d_in[1];
  const float* wq = (const float*)d_in[2];
  const float* bq = (const float*)d_in[3];
  const float* wk = (const float*)d_in[4];
  const float* bk = (const float*)d_in[5];
  const float* wv = (const float*)d_in[6];
  const float* bv = (const float*)d_in[7];
  const float* wo = (const float*)d_in[8];
  const float* bo = (const float*)d_in[9];
  char* ws = (char*)d_ws;
  int*   cnts    = (int*)(ws + OFF_CNT);
  short* xb      = (short*)(ws + OFF_XB);
  short* Wqkv    = (short*)(ws + OFF_WQKV);
  float* bqkv    = (float*)(ws + OFF_BQKV);
  short* wob     = (short*)(ws + OFF_WOB);
  float* bof     = (float*)(ws + OFF_BO);
  short* Qw      = (short*)(ws + OFF_Q);
  short* Kw      = (short*)(ws + OFF_K);
  short* Vw      = (short*)(ws + OFF_V);
  short* Vtw     = (short*)(ws + OFF_VT);
  // overlays (lifetimes verified):
  short* Kc      = (short*)(ws + OFF_XB);             // xb dead after gemm<0>
  short* OP0     = (short*)(ws + OFF_K);              // K dead after gather
  short* OP1     = (short*)(ws + OFF_V);              // V dead after gather
  float* Lp      = (float*)(ws + OFF_O);              // written by attn only
  // idxC: written by prep_scan (blocks 0-1), read by gather, dead after.
  int* idxSafe = (int*)(ws + OFF_O);

  prep_scan_kernel<<<1155, 256, 0, stream>>>(x, wq, bq, wk, bk, wv, bv, wo, bo,
                                             xb, Wqkv, bqkv, wob, bof,
                                             mask, idxSafe, cnts);
  gemm_kernel<0><<<dim3(64, 12), 256, 0, stream>>>(xb, Wqkv, bqkv, Qw, Kw, Vw,
                                                   nullptr, nullptr, nullptr, nullptr);
  gather_kv_kernel<<<dim3(64, 16), 256, 0, stream>>>(Kw, Vw, idxSafe, cnts, Kc, Vtw);
  attn_kernel<<<dim3(16, 16, 2), 256, 0, stream>>>(Qw, Kc, Vtw, cnts, OP0, OP1, Lp);
  gemm_kernel<1><<<dim3(64, 4), 256, 0, stream>>>(OP0, wob, bof,
                                                  nullptr, nullptr, nullptr, (float*)d_out,
                                                  OP1, Lp, cnts);
}